// Round 4
// baseline (407.214 us; speedup 1.0000x reference)
//
#include <hip/hip_runtime.h>
#include <hip/hip_bf16.h>

#define NN   100000
#define NE   1600000
#define FIN  256
#define HID  32
#define OUTD 16
#define NBLK ((NN + 255) / 256)   // 391 scan blocks

#define BM          64
#define GEMM_BLOCKS ((NN + BM - 1) / BM)                 // 1563
#define CNT_EDGES   2048
#define CNT_BLOCKS  ((NE + CNT_EDGES - 1) / CNT_EDGES)   // 782
#define FILLB       1024
#define FILL_BLOCKS ((NE + FILLB - 1) / FILLB)           // 1563
#define FG_BLOCKS   (GEMM_BLOCKS + FILL_BLOCKS)          // 3126

// ---- workspace layout (32-bit word offsets), total ~9.1M words = 36.4 MB ----
#define OFF_FLAG    0                      // [0]=is64, [1]=isf32
#define OFF_DEG8    64                     // 8*NN u32: replica-major [rep][node]
#define OFF_DEGTOT  (OFF_DEG8 + 8*NN)      // NN u32 total counts
#define OFF_DINV    (OFF_DEGTOT + NN)      // NN floats
#define OFF_BSUM    (OFF_DINV + NN)        // 1024 ints
#define OFF_ROWPTR  (OFF_BSUM + 1024)      // NN+1 ints
#define OFF_CSR     (OFF_ROWPTR + NN + 32) // 2*NE words (int2 pairs), 8B-aligned
#define OFF_H1      (OFF_CSR + 2*NE)       // NN*HID floats
#define OFF_P2      (OFF_H1 + NN*HID)      // NN*OUTD floats

#define CSHIFT 26
#define CMASK  ((1u << CSHIFT) - 1u)
#define WSCALE 1048576.0f                  // 2^20
#define WINV   (1.0f / 1048576.0f)

__device__ __forceinline__ float bf2f(unsigned short u) {
  union { unsigned int i; float f; } v; v.i = ((unsigned int)u) << 16; return v.f;
}
__device__ __forceinline__ unsigned short f2bf(float f) {
  union { float f; unsigned int i; } v; v.f = f;
  unsigned int x = v.i;
  return (unsigned short)((x + 0x7fffu + ((x >> 16) & 1u)) >> 16); // RNE
}
__device__ __forceinline__ int eidx(const int* __restrict__ ei, long long pos, int is64) {
  return is64 ? ei[2 * pos] : ei[pos];
}
__device__ __forceinline__ float ldf(const void* p, long long i, int isf32) {
  return isf32 ? ((const float*)p)[i] : bf2f(((const unsigned short*)p)[i]);
}

// ---- K0: detect flags (block 0) + zero deg8 (blocks 1..) ----
__global__ __launch_bounds__(256) void detect_zero_kernel(const int* __restrict__ ei,
    const unsigned short* __restrict__ xu, int* __restrict__ flags,
    unsigned int* __restrict__ zp, int zn) {
  int b = blockIdx.x;
  if (b == 0) {
    __shared__ int any, cnt;
    if (threadIdx.x == 0) { any = 0; cnt = 0; }
    __syncthreads();
    int local = 0, c = 0;
    for (int i = threadIdx.x; i < 2048; i += 256) local |= ei[2 * i + 1];
    for (int i = threadIdx.x; i < 1024; i += 256) {
      unsigned int e = (xu[2 * i] >> 7) & 0xFF;
      c += (e < 100 || e > 140) ? 1 : 0;
    }
    if (local) atomicOr(&any, 1);
    atomicAdd(&cnt, c);
    __syncthreads();
    if (threadIdx.x == 0) {
      flags[0] = (any == 0) ? 1 : 0;   // 1 => int64 layout
      flags[1] = (cnt > 100) ? 1 : 0;  // 1 => f32 floats
    }
  } else {
    int stride = (gridDim.x - 1) * 256;
    for (int i = (b - 1) * 256 + threadIdx.x; i < zn; i += stride) zp[i] = 0u;
  }
}

// ---- K1: count — fire-and-forget replicated atomics, NO return, NO rank ----
__global__ __launch_bounds__(256) void count_kernel(const int* __restrict__ ei,
    const void* __restrict__ ew, unsigned int* __restrict__ deg8,
    const int* __restrict__ flags) {
  int t = threadIdx.x;
  int is64 = flags[0], isf32 = flags[1];
  int e0 = blockIdx.x * CNT_EDGES + t;
  int c[8]; float w[8];
  #pragma unroll
  for (int q = 0; q < 8; q++) {
    int e = e0 + q * 256;
    if (e < NE) {
      c[q] = eidx(ei, (long long)NE + e, is64);
      w[q] = ldf(ew, e, isf32);
    } else c[q] = -1;
  }
  #pragma unroll
  for (int q = 0; q < 8; q++) {
    if (c[q] >= 0) {
      int e = e0 + q * 256;
      unsigned int inc = (1u << CSHIFT) | (unsigned int)(w[q] * WSCALE + 0.5f);
      atomicAdd(deg8 + (unsigned)(e & 7) * NN + c[q], inc);  // result unused -> no-return atomic
    }
  }
}

// ---- K2: per-node stats — sum 8 replicas -> degtot, dinv, block sums ----
__global__ __launch_bounds__(256) void node_stats_kernel(
    const unsigned int* __restrict__ deg8, unsigned int* __restrict__ degtot,
    float* __restrict__ dinv, int* __restrict__ bsum) {
  __shared__ int s[256];
  int t = threadIdx.x;
  int i = blockIdx.x * 256 + t;
  unsigned int cnt = 0, ws = 0;
  if (i < NN) {
    #pragma unroll
    for (int r = 0; r < 8; r++) {
      unsigned int v = deg8[(unsigned)r * NN + i];
      cnt += v >> CSHIFT;
      ws  += v & CMASK;
    }
    degtot[i] = cnt;
    dinv[i] = rsqrtf((float)ws * WINV + 1.0f);   // + self-loop
  }
  s[t] = (int)cnt;
  __syncthreads();
  for (int off = 128; off > 0; off >>= 1) {
    if (t < off) s[t] += s[t + off];
    __syncthreads();
  }
  if (t == 0) bsum[blockIdx.x] = s[0];
}

// ---- K3: scan -> rowptr; convert deg8 replicas to absolute write cursors ----
__global__ __launch_bounds__(256) void scan_write_kernel(const unsigned int* __restrict__ degtot,
    const int* __restrict__ bsum, int* __restrict__ rowptr,
    unsigned int* __restrict__ deg8) {
  __shared__ int a[256];
  __shared__ int base_s;
  int t = threadIdx.x;
  int b = blockIdx.x;
  int v = 0;
  for (int i = t; i < NBLK; i += 256) v += (i < b) ? bsum[i] : 0;
  a[t] = v;
  __syncthreads();
  for (int off = 128; off > 0; off >>= 1) {
    if (t < off) a[t] += a[t + off];
    __syncthreads();
  }
  if (t == 0) base_s = a[0];
  __syncthreads();
  int base = base_s;
  int i = b * 256 + t;
  int orig = (i < NN) ? (int)degtot[i] : 0;
  a[t] = orig;
  __syncthreads();
  for (int off = 1; off < 256; off <<= 1) {
    int x2 = a[t] + ((t >= off) ? a[t - off] : 0);
    __syncthreads();
    a[t] = x2;
    __syncthreads();
  }
  if (i < NN) {
    int pos = base + a[t] - orig;    // exclusive
    rowptr[i] = pos;
    unsigned int run = (unsigned int)pos;
    #pragma unroll
    for (int r = 0; r < 8; r++) {
      unsigned int pv = deg8[(unsigned)r * NN + i];
      deg8[(unsigned)r * NN + i] = run;          // absolute cursor for (node, rep)
      run += pv >> CSHIFT;
    }
  }
  if (b == 0 && t == 0) rowptr[NN] = NE;
}

// ---- K4 FUSED: gemm1 (even blocks) + fill_csr (odd blocks) ----
// LDS 13KB -> no occupancy cap; fill's atomic latency hides under gemm FMAs.
__global__ __launch_bounds__(256, 8) void gemm_fill_kernel(const void* __restrict__ x,
    const void* __restrict__ W1, float* __restrict__ h1,
    const int* __restrict__ ei, const void* __restrict__ ew,
    const float* __restrict__ dinv, unsigned int* __restrict__ deg8,
    int2* __restrict__ csr, const int* __restrict__ flags) {
  __shared__ float xs[32][BM + 2];   // stride 66
  __shared__ float wl[32][36];
  int b = blockIdx.x;
  int t = threadIdx.x;
  int isf32 = flags[1];

  if (b & 1) {
    // ---- fill_csr body: cursor atomics give CSR slot directly ----
    int is64 = flags[0];
    int fid = b >> 1;
    int e0 = fid * FILLB + t;
    int r[4], c[4]; float w[4];
    #pragma unroll
    for (int q = 0; q < 4; q++) {
      int e = e0 + q * 256;
      if (e < NE) {
        r[q] = eidx(ei, e, is64);
        c[q] = eidx(ei, (long long)NE + e, is64);
        w[q] = ldf(ew, e, isf32);
      } else c[q] = -1;
    }
    float dr[4], dc[4];
    #pragma unroll
    for (int q = 0; q < 4; q++) {
      if (c[q] >= 0) { dr[q] = dinv[r[q]]; dc[q] = dinv[c[q]]; }
    }
    unsigned int pos[4];
    #pragma unroll
    for (int q = 0; q < 4; q++) {
      if (c[q] >= 0) {
        int e = e0 + q * 256;
        pos[q] = atomicAdd(deg8 + (unsigned)(e & 7) * NN + c[q], 1u);
      }
    }
    #pragma unroll
    for (int q = 0; q < 4; q++) {
      if (c[q] >= 0) {
        int2 pr; pr.x = r[q]; pr.y = __float_as_int(dr[q] * w[q] * dc[q]);
        csr[pos[q]] = pr;
      }
    }
    return;
  }

  // ---- gemm1 body: h1 = x @ W1. BM=64, W stripe-staged ----
  int rb = (b >> 1) * BM;
  int j0 = (t & 15) * 2;        // output col pair
  int r0 = (t >> 4) * 4;        // 4 output rows
  int rr  = t >> 2;             // staging row 0..63
  int kk0 = (t & 3) * 8;        // staging k chunk (8 elems)
  int kkw = t >> 3;             // W staging row 0..31
  int mw  = (t & 7) * 4;        // W staging col (4 elems)
  long long grow = (long long)rb + rr;

  float acc[4][2];
  #pragma unroll
  for (int i = 0; i < 4; i++) { acc[i][0] = 0.f; acc[i][1] = 0.f; }

  union Pf { uint4 u[2]; float f[8]; unsigned short s[16]; } pfx;
  uint4 pw;

#define LOADX(kc_) do {                                                        \
    if (grow < NN) {                                                           \
      if (isf32) {                                                             \
        const float* xp_ = (const float*)x + grow * FIN + (kc_) + kk0;         \
        pfx.u[0] = ((const uint4*)xp_)[0];                                     \
        pfx.u[1] = ((const uint4*)xp_)[1];                                     \
      } else {                                                                 \
        const unsigned short* xp_ = (const unsigned short*)x + grow * FIN + (kc_) + kk0; \
        pfx.u[0] = *(const uint4*)xp_;                                         \
      }                                                                        \
    }                                                                          \
  } while (0)

#define STOREX() do {                                                          \
    bool ok_ = grow < NN;                                                      \
    if (isf32) {                                                               \
      _Pragma("unroll")                                                        \
      for (int q = 0; q < 8; q++) xs[kk0 + q][rr] = ok_ ? pfx.f[q] : 0.f;      \
    } else {                                                                   \
      _Pragma("unroll")                                                        \
      for (int q = 0; q < 8; q++) xs[kk0 + q][rr] = ok_ ? bf2f(pfx.s[q]) : 0.f;\
    }                                                                          \
  } while (0)

#define LOADW(kc_) do {                                                        \
    if (isf32) {                                                               \
      pw = *(const uint4*)((const float*)W1 + ((kc_) + kkw) * HID + mw);       \
    } else {                                                                   \
      const unsigned short* wp_ = (const unsigned short*)W1 + ((kc_) + kkw) * HID + mw; \
      pw.x = ((const unsigned int*)wp_)[0];                                    \
      pw.y = ((const unsigned int*)wp_)[1];                                    \
    }                                                                          \
  } while (0)

#define STOREW() do {                                                          \
    if (isf32) {                                                               \
      *(float4*)&wl[kkw][mw] = *(float4*)&pw;                                  \
    } else {                                                                   \
      const unsigned short* ps_ = (const unsigned short*)&pw;                  \
      wl[kkw][mw + 0] = bf2f(ps_[0]); wl[kkw][mw + 1] = bf2f(ps_[1]);          \
      wl[kkw][mw + 2] = bf2f(ps_[2]); wl[kkw][mw + 3] = bf2f(ps_[3]);          \
    }                                                                          \
  } while (0)

  LOADX(0); LOADW(0);

  for (int kc = 0; kc < FIN; kc += 32) {
    __syncthreads();
    STOREX(); STOREW();
    __syncthreads();
    if (kc + 32 < FIN) { LOADX(kc + 32); LOADW(kc + 32); }
    #pragma unroll 8
    for (int kk = 0; kk < 32; kk++) {
      float2 wp2 = *(const float2*)&wl[kk][j0];
      float2 xa = *(const float2*)&xs[kk][r0];
      float2 xb = *(const float2*)&xs[kk][r0 + 2];
      float xv[4] = {xa.x, xa.y, xb.x, xb.y};
      #pragma unroll
      for (int i = 0; i < 4; i++) {
        acc[i][0] = fmaf(xv[i], wp2.x, acc[i][0]);
        acc[i][1] = fmaf(xv[i], wp2.y, acc[i][1]);
      }
    }
  }

  #pragma unroll
  for (int i = 0; i < 4; i++) {
    int g = rb + r0 + i;
    if (g < NN) {
      float2 v2; v2.x = acc[i][0]; v2.y = acc[i][1];
      *((float2*)(h1 + (long long)g * HID + j0)) = v2;
    }
  }
#undef LOADX
#undef STOREX
#undef LOADW
#undef STOREW
}

// ---- gather1 fused: conv1 aggregate + self-loop + bias + ReLU + @W2 -> p2 ----
__global__ __launch_bounds__(256) void gather1_kernel(const float* __restrict__ h1,
    const float* __restrict__ dinv, const int* __restrict__ rowptr,
    const int2* __restrict__ csr, const void* __restrict__ b1,
    const void* __restrict__ W2, float* __restrict__ p2,
    const int* __restrict__ flags) {
  __shared__ float w2lds[HID * OUTD];  // [k][m] flat
  __shared__ float b1l[HID];
  __shared__ float tl[8][HID + 1];
  int t = threadIdx.x;
  int isf32 = flags[1];
  w2lds[2 * t]     = ldf(W2, 2 * t, isf32);
  w2lds[2 * t + 1] = ldf(W2, 2 * t + 1, isf32);
  if (t < HID) b1l[t] = ldf(b1, t, isf32);
  __syncthreads();

  int nl = t >> 5;          // node slot 0..7
  int j  = t & 31;          // feature
  int node = blockIdx.x * 8 + nl;
  if (node < NN) {
    int k0 = rowptr[node], k1 = rowptr[node + 1];
    float acc = 0.f;
    int k = k0;
    for (; k + 8 <= k1; k += 8) {
      int2 q0 = csr[k];     int2 q1 = csr[k + 1];
      int2 q2 = csr[k + 2]; int2 q3 = csr[k + 3];
      int2 q4 = csr[k + 4]; int2 q5 = csr[k + 5];
      int2 q6 = csr[k + 6]; int2 q7 = csr[k + 7];
      float v0 = h1[q0.x * HID + j]; float v1 = h1[q1.x * HID + j];
      float v2 = h1[q2.x * HID + j]; float v3 = h1[q3.x * HID + j];
      float v4 = h1[q4.x * HID + j]; float v5 = h1[q5.x * HID + j];
      float v6 = h1[q6.x * HID + j]; float v7 = h1[q7.x * HID + j];
      acc = fmaf(__int_as_float(q0.y), v0, acc);
      acc = fmaf(__int_as_float(q1.y), v1, acc);
      acc = fmaf(__int_as_float(q2.y), v2, acc);
      acc = fmaf(__int_as_float(q3.y), v3, acc);
      acc = fmaf(__int_as_float(q4.y), v4, acc);
      acc = fmaf(__int_as_float(q5.y), v5, acc);
      acc = fmaf(__int_as_float(q6.y), v6, acc);
      acc = fmaf(__int_as_float(q7.y), v7, acc);
    }
    for (; k + 4 <= k1; k += 4) {
      int2 q0 = csr[k];     int2 q1 = csr[k + 1];
      int2 q2 = csr[k + 2]; int2 q3 = csr[k + 3];
      float v0 = h1[q0.x * HID + j]; float v1 = h1[q1.x * HID + j];
      float v2 = h1[q2.x * HID + j]; float v3 = h1[q3.x * HID + j];
      acc = fmaf(__int_as_float(q0.y), v0, acc);
      acc = fmaf(__int_as_float(q1.y), v1, acc);
      acc = fmaf(__int_as_float(q2.y), v2, acc);
      acc = fmaf(__int_as_float(q3.y), v3, acc);
    }
    for (; k < k1; k++) {
      int2 pr = csr[k];
      acc = fmaf(__int_as_float(pr.y), h1[pr.x * HID + j], acc);
    }
    float di = dinv[node];
    acc = fmaf(di * di, h1[node * HID + j], acc);
    acc += b1l[j];
    tl[nl][j] = fmaxf(acc, 0.f);
  }
  __syncthreads();
  int m = t & 31;
  if (node < NN && m < OUTD) {
    float s = 0.f;
    #pragma unroll
    for (int k = 0; k < HID; k++) s = fmaf(tl[nl][k], w2lds[k * OUTD + m], s);
    p2[node * OUTD + m] = s;
  }
}

// ---- gather2: conv2 aggregate + self-loop + bias -> out ----
__global__ __launch_bounds__(256) void gather2_kernel(const float* __restrict__ p2,
    const float* __restrict__ dinv, const int* __restrict__ rowptr,
    const int2* __restrict__ csr, const void* __restrict__ b2,
    void* __restrict__ out, const int* __restrict__ flags) {
  __shared__ float b2l[OUTD];
  int t = threadIdx.x;
  int isf32 = flags[1];
  if (t < OUTD) b2l[t] = ldf(b2, t, isf32);
  __syncthreads();

  int nl = t >> 4;
  int m  = t & 15;
  int node = blockIdx.x * 16 + nl;
  if (node >= NN) return;
  int k0 = rowptr[node], k1 = rowptr[node + 1];
  float acc = 0.f;
  int k = k0;
  for (; k + 8 <= k1; k += 8) {
    int2 q0 = csr[k];     int2 q1 = csr[k + 1];
    int2 q2 = csr[k + 2]; int2 q3 = csr[k + 3];
    int2 q4 = csr[k + 4]; int2 q5 = csr[k + 5];
    int2 q6 = csr[k + 6]; int2 q7 = csr[k + 7];
    float v0 = p2[q0.x * OUTD + m]; float v1 = p2[q1.x * OUTD + m];
    float v2 = p2[q2.x * OUTD + m]; float v3 = p2[q3.x * OUTD + m];
    float v4 = p2[q4.x * OUTD + m]; float v5 = p2[q5.x * OUTD + m];
    float v6 = p2[q6.x * OUTD + m]; float v7 = p2[q7.x * OUTD + m];
    acc = fmaf(__int_as_float(q0.y), v0, acc);
    acc = fmaf(__int_as_float(q1.y), v1, acc);
    acc = fmaf(__int_as_float(q2.y), v2, acc);
    acc = fmaf(__int_as_float(q3.y), v3, acc);
    acc = fmaf(__int_as_float(q4.y), v4, acc);
    acc = fmaf(__int_as_float(q5.y), v5, acc);
    acc = fmaf(__int_as_float(q6.y), v6, acc);
    acc = fmaf(__int_as_float(q7.y), v7, acc);
  }
  for (; k + 4 <= k1; k += 4) {
    int2 q0 = csr[k];     int2 q1 = csr[k + 1];
    int2 q2 = csr[k + 2]; int2 q3 = csr[k + 3];
    float v0 = p2[q0.x * OUTD + m]; float v1 = p2[q1.x * OUTD + m];
    float v2 = p2[q2.x * OUTD + m]; float v3 = p2[q3.x * OUTD + m];
    acc = fmaf(__int_as_float(q0.y), v0, acc);
    acc = fmaf(__int_as_float(q1.y), v1, acc);
    acc = fmaf(__int_as_float(q2.y), v2, acc);
    acc = fmaf(__int_as_float(q3.y), v3, acc);
  }
  for (; k < k1; k++) {
    int2 pr = csr[k];
    acc = fmaf(__int_as_float(pr.y), p2[pr.x * OUTD + m], acc);
  }
  float di = dinv[node];
  acc = fmaf(di * di, p2[node * OUTD + m], acc);
  acc += b2l[m];
  int oidx = node * OUTD + m;
  if (isf32) ((float*)out)[oidx] = acc;
  else       ((unsigned short*)out)[oidx] = f2bf(acc);
}

extern "C" void kernel_launch(void* const* d_in, const int* in_sizes, int n_in,
                              void* d_out, int out_size, void* d_ws, size_t ws_size,
                              hipStream_t stream) {
  const void* x  = d_in[0];
  const int* ei  = (const int*)d_in[1];
  const void* ew = d_in[2];
  const void* W1 = d_in[3];
  const void* b1 = d_in[4];
  const void* W2 = d_in[5];
  const void* b2 = d_in[6];
  float* ws = (float*)d_ws;
  int* wsi = (int*)d_ws;
  unsigned int* deg8 = (unsigned int*)(wsi + OFF_DEG8);
  unsigned int* degtot = (unsigned int*)(wsi + OFF_DEGTOT);

  detect_zero_kernel<<<dim3(513), dim3(256), 0, stream>>>(ei, (const unsigned short*)x,
      wsi + OFF_FLAG, deg8, 8 * NN);
  count_kernel<<<dim3(CNT_BLOCKS), dim3(256), 0, stream>>>(ei, ew, deg8, wsi + OFF_FLAG);
  node_stats_kernel<<<dim3(NBLK), dim3(256), 0, stream>>>(deg8, degtot, ws + OFF_DINV,
      wsi + OFF_BSUM);
  scan_write_kernel<<<dim3(NBLK), dim3(256), 0, stream>>>(degtot, wsi + OFF_BSUM,
      wsi + OFF_ROWPTR, deg8);
  gemm_fill_kernel<<<dim3(FG_BLOCKS), dim3(256), 0, stream>>>(x, W1, ws + OFF_H1,
      ei, ew, ws + OFF_DINV, deg8, (int2*)(wsi + OFF_CSR), wsi + OFF_FLAG);
  gather1_kernel<<<dim3((NN + 7) / 8), dim3(256), 0, stream>>>(ws + OFF_H1, ws + OFF_DINV,
      wsi + OFF_ROWPTR, (const int2*)(wsi + OFF_CSR), b1, W2, ws + OFF_P2, wsi + OFF_FLAG);
  gather2_kernel<<<dim3((NN + 15) / 16), dim3(256), 0, stream>>>(ws + OFF_P2, ws + OFF_DINV,
      wsi + OFF_ROWPTR, (const int2*)(wsi + OFF_CSR), b2, d_out, wsi + OFF_FLAG);
}

// Round 5
// 349.099 us; speedup vs baseline: 1.1665x; 1.1665x over previous
//
#include <hip/hip_runtime.h>
#include <hip/hip_bf16.h>

#define NN   100000
#define NE   1600000
#define FIN  256
#define HID  32
#define OUTD 16
#define NBLK ((NN + 255) / 256)   // 391 scan blocks

#define GEMM_ROWS   64
#define GEMM_BLOCKS ((NN + GEMM_ROWS - 1) / GEMM_ROWS)   // 1563
#define CNT_EDGES   2048
#define CNT_BLOCKS  ((NE + CNT_EDGES - 1) / CNT_EDGES)   // 782
#define FUSE_BLOCKS (GEMM_BLOCKS + CNT_BLOCKS)           // 2345
#define FILL_BLOCKS ((NE + 1023) / 1024)                 // 1563

// ---- workspace layout (32-bit word offsets) ----
#define OFF_FLAG    0                      // [0]=is64, [1]=isf32
#define OFF_DEGPACK 64                     // NN u64 (2*NN words), 8B-aligned
#define OFF_DINV    (OFF_DEGPACK + 2*NN)   // NN floats
#define OFF_RANK    (OFF_DINV + NN)        // NE ints
#define OFF_BSUM    (OFF_RANK + NE)        // 512 ints (+512 pad)
#define OFF_ROWPTR  (OFF_BSUM + 1024)      // NN+1 ints
#define OFF_CSR     (OFF_ROWPTR + NN + 32) // 2*NE words (int2 pairs), 8B-aligned
#define OFF_H1      (OFF_CSR + 2*NE)       // NN*HID floats
#define OFF_P2      (OFF_H1 + NN*HID)      // NN*OUTD floats

#define PACK_SHIFT 40
#define PACK_MASK  ((1ull << PACK_SHIFT) - 1ull)
#define FP_SCALE   16777216.0f             // 2^24
#define FP_INV     (1.0f / 16777216.0f)

__device__ __forceinline__ float bf2f(unsigned short u) {
  union { unsigned int i; float f; } v; v.i = ((unsigned int)u) << 16; return v.f;
}
__device__ __forceinline__ unsigned short f2bf(float f) {
  union { float f; unsigned int i; } v; v.f = f;
  unsigned int x = v.i;
  return (unsigned short)((x + 0x7fffu + ((x >> 16) & 1u)) >> 16); // RNE
}
__device__ __forceinline__ int eidx(const int* __restrict__ ei, long long pos, int is64) {
  return is64 ? ei[2 * pos] : ei[pos];
}
__device__ __forceinline__ float ldf(const void* p, long long i, int isf32) {
  return isf32 ? ((const float*)p)[i] : bf2f(((const unsigned short*)p)[i]);
}

// ---- K0: detect flags (block 0) + zero degpack (blocks 1..) ----
__global__ __launch_bounds__(256) void detect_zero_kernel(const int* __restrict__ ei,
    const unsigned short* __restrict__ xu, int* __restrict__ flags,
    float* __restrict__ zp, int zn) {
  int b = blockIdx.x;
  if (b == 0) {
    __shared__ int any, cnt;
    if (threadIdx.x == 0) { any = 0; cnt = 0; }
    __syncthreads();
    int local = 0, c = 0;
    for (int i = threadIdx.x; i < 2048; i += 256) local |= ei[2 * i + 1];
    for (int i = threadIdx.x; i < 1024; i += 256) {
      unsigned int e = (xu[2 * i] >> 7) & 0xFF;
      c += (e < 100 || e > 140) ? 1 : 0;
    }
    if (local) atomicOr(&any, 1);
    atomicAdd(&cnt, c);
    __syncthreads();
    if (threadIdx.x == 0) {
      flags[0] = (any == 0) ? 1 : 0;   // 1 => int64 layout
      flags[1] = (cnt > 100) ? 1 : 0;  // 1 => f32 floats
    }
  } else {
    int stride = (gridDim.x - 1) * 256;
    for (int i = (b - 1) * 256 + threadIdx.x; i < zn; i += stride) zp[i] = 0.f;
  }
}

// ---- K1 FUSED: count_rank (atomic-latency-bound, ILP=8) + gemm1 (prefetched) ----
// Every 3rd block (b%3==0) is a count block (782); the rest are gemm blocks (1563).
// LDS = 32KB (W) + 8KB (x tile) = 40960 B exactly -> 4 blocks/CU (16 waves).
// [R1-proven config: 93 us measured. Do not restructure without A/B.]
__global__ __launch_bounds__(256) void count_gemm_kernel(const int* __restrict__ ei,
    const void* __restrict__ ew, unsigned long long* __restrict__ degpack,
    int* __restrict__ rank, const void* __restrict__ x,
    const void* __restrict__ W1, float* __restrict__ h1,
    const int* __restrict__ flags) {
  __shared__ float wlds[FIN * HID];          // 32 KB, [k][j] flat
  __shared__ float xs[32][GEMM_ROWS];        // 8 KB, [kk][row]
  int b = blockIdx.x;
  int t = threadIdx.x;

  if ((b % 3) == 0) {
    // ---- count_rank body: 8 edges/thread, 8 atomics in flight ----
    int cid = b / 3;
    int is64 = flags[0], isf32 = flags[1];
    int e0 = cid * CNT_EDGES + t;
    int c[8]; float w[8];
    #pragma unroll
    for (int q = 0; q < 8; q++) {
      int e = e0 + q * 256;
      if (e < NE) {
        c[q] = eidx(ei, (long long)NE + e, is64);
        w[q] = ldf(ew, e, isf32);
      } else c[q] = -1;
    }
    unsigned long long old[8];
    #pragma unroll
    for (int q = 0; q < 8; q++) {
      if (c[q] >= 0) {
        unsigned long long inc = (1ull << PACK_SHIFT)
                               | (unsigned long long)(w[q] * FP_SCALE + 0.5f);
        old[q] = atomicAdd(degpack + c[q], inc);
      }
    }
    #pragma unroll
    for (int q = 0; q < 8; q++)
      if (c[q] >= 0) rank[e0 + q * 256] = (int)(old[q] >> PACK_SHIFT);
    return;
  }

  // ---- gemm1 body: h1 = x @ W1, 64-row tile, register-prefetched K loop ----
  int gid = b - b / 3 - 1;                 // bijective onto 0..GEMM_BLOCKS-1
  int rb = gid * GEMM_ROWS;
  int isf32 = flags[1];

  // stage W1 (one row per thread)
  if (isf32) {
    const float* wrow = (const float*)W1 + t * HID;
    #pragma unroll
    for (int jj = 0; jj < HID; jj += 4)
      *(float4*)&wlds[t * HID + jj] = *((const float4*)(wrow + jj));
  } else {
    const unsigned short* wrow = (const unsigned short*)W1 + t * HID;
    #pragma unroll
    for (int jj = 0; jj < HID; jj += 8) {
      uint4 pk = *((const uint4*)(wrow + jj));
      const unsigned short* pu = (const unsigned short*)&pk;
      #pragma unroll
      for (int q = 0; q < 8; q++) wlds[t * HID + jj + q] = bf2f(pu[q]);
    }
  }

  int j0 = (t & 15) * 2;        // output col pair
  int r0 = (t >> 4) * 4;        // 4 output rows
  int rr  = t >> 2;             // staging row 0..63
  int kk0 = (t & 3) * 8;        // staging k chunk
  long long grow = (long long)rb + rr;
  float acc[4][2];
  #pragma unroll
  for (int i = 0; i < 4; i++) { acc[i][0] = 0.f; acc[i][1] = 0.f; }

  union { uint4 u[2]; float f[8]; unsigned short s[16]; } pf;

  // prologue prefetch of tile kc=0
  {
    if (grow < NN) {
      if (isf32) {
        const float* xp = (const float*)x + grow * FIN + kk0;
        pf.u[0] = ((const uint4*)xp)[0];
        pf.u[1] = ((const uint4*)xp)[1];
      } else {
        const unsigned short* xp = (const unsigned short*)x + grow * FIN + kk0;
        pf.u[0] = *(const uint4*)xp;
      }
    } else { pf.u[0] = make_uint4(0,0,0,0); pf.u[1] = make_uint4(0,0,0,0); }
  }

  for (int kc = 0; kc < FIN; kc += 32) {
    __syncthreads();   // previous compute done reading xs (iter0: W writes done)
    if (isf32) {
      #pragma unroll
      for (int q = 0; q < 8; q++) xs[kk0 + q][rr] = pf.f[q];
    } else {
      #pragma unroll
      for (int q = 0; q < 8; q++) xs[kk0 + q][rr] = bf2f(pf.s[q]);
    }
    __syncthreads();
    // prefetch next tile into registers (hides under the FMA loop below)
    if (kc + 32 < FIN) {
      if (grow < NN) {
        if (isf32) {
          const float* xp = (const float*)x + grow * FIN + kc + 32 + kk0;
          pf.u[0] = ((const uint4*)xp)[0];
          pf.u[1] = ((const uint4*)xp)[1];
        } else {
          const unsigned short* xp = (const unsigned short*)x + grow * FIN + kc + 32 + kk0;
          pf.u[0] = *(const uint4*)xp;
        }
      }
    }
    #pragma unroll 8
    for (int kk = 0; kk < 32; kk++) {
      float2 wp = *(const float2*)&wlds[(kc + kk) * HID + j0];
      float4 xv = *(const float4*)&xs[kk][r0];
      float xr[4] = {xv.x, xv.y, xv.z, xv.w};
      #pragma unroll
      for (int i = 0; i < 4; i++) {
        acc[i][0] = fmaf(xr[i], wp.x, acc[i][0]);
        acc[i][1] = fmaf(xr[i], wp.y, acc[i][1]);
      }
    }
  }
  #pragma unroll
  for (int i = 0; i < 4; i++) {
    int g = rb + r0 + i;
    if (g < NN) {
      float2 v; v.x = acc[i][0]; v.y = acc[i][1];
      *((float2*)(h1 + (long long)g * HID + j0)) = v;
    }
  }
}

// ---- K2 FUSED: scan_sum (blocks 0..390) + dinv (blocks 391..781) ----
__global__ __launch_bounds__(256) void dinv_scansum_kernel(
    const unsigned long long* __restrict__ degpack, float* __restrict__ dinv,
    int* __restrict__ bsum) {
  int b = blockIdx.x;
  if (b < NBLK) {
    __shared__ int s[256];
    int i = b * 256 + threadIdx.x;
    s[threadIdx.x] = (i < NN) ? (int)(degpack[i] >> PACK_SHIFT) : 0;
    __syncthreads();
    for (int off = 128; off > 0; off >>= 1) {
      if (threadIdx.x < off) s[threadIdx.x] += s[threadIdx.x + off];
      __syncthreads();
    }
    if (threadIdx.x == 0) bsum[b] = s[0];
  } else {
    int i = (b - NBLK) * 256 + threadIdx.x;
    if (i >= NN) return;
    float d = (float)(degpack[i] & PACK_MASK) * FP_INV + 1.0f;  // + self-loop
    dinv[i] = rsqrtf(d);
  }
}

// ---- scan: write rowptr; each block reduces bsum prefix itself ----
__global__ __launch_bounds__(256) void scan_write_kernel(const unsigned long long* __restrict__ degpack,
    const int* __restrict__ bsum, int* __restrict__ rowptr) {
  __shared__ int a[256];
  __shared__ int base_s;
  int t = threadIdx.x;
  int b = blockIdx.x;
  int v = 0;
  for (int i = t; i < NBLK; i += 256) v += (i < b) ? bsum[i] : 0;
  a[t] = v;
  __syncthreads();
  for (int off = 128; off > 0; off >>= 1) {
    if (t < off) a[t] += a[t + off];
    __syncthreads();
  }
  if (t == 0) base_s = a[0];
  __syncthreads();
  int base = base_s;
  int i = b * 256 + t;
  int orig = (i < NN) ? (int)(degpack[i] >> PACK_SHIFT) : 0;
  a[t] = orig;
  __syncthreads();
  for (int off = 1; off < 256; off <<= 1) {
    int x2 = a[t] + ((t >= off) ? a[t - off] : 0);
    __syncthreads();
    a[t] = x2;
    __syncthreads();
  }
  if (i < NN) rowptr[i] = base + a[t] - orig;  // exclusive
  if (b == 0 && t == 0) rowptr[NN] = NE;
}

// ---- fill CSR: (src, norm) pairs bucketed by dst — NO atomics, 4 edges/thread ----
__global__ __launch_bounds__(256) void fill_csr_kernel(const int* __restrict__ ei,
    const void* __restrict__ ew, const float* __restrict__ dinv,
    const int* __restrict__ rowptr, const int* __restrict__ rank,
    int2* __restrict__ csr, const int* __restrict__ flags) {
  int is64 = flags[0], isf32 = flags[1];
  int e0 = blockIdx.x * 1024 + threadIdx.x;
  int r[4], c[4], rk[4]; float w[4];
  #pragma unroll
  for (int q = 0; q < 4; q++) {
    int e = e0 + q * 256;
    if (e < NE) {
      r[q]  = eidx(ei, e, is64);
      c[q]  = eidx(ei, (long long)NE + e, is64);
      w[q]  = ldf(ew, e, isf32);
      rk[q] = rank[e];
    } else c[q] = -1;
  }
  float dr[4], dc[4]; int rp[4];
  #pragma unroll
  for (int q = 0; q < 4; q++) {
    if (c[q] >= 0) {
      dr[q] = dinv[r[q]];
      dc[q] = dinv[c[q]];
      rp[q] = rowptr[c[q]];
    }
  }
  #pragma unroll
  for (int q = 0; q < 4; q++) {
    if (c[q] >= 0) {
      int2 pr; pr.x = r[q]; pr.y = __float_as_int(dr[q] * w[q] * dc[q]);
      csr[rp[q] + rk[q]] = pr;
    }
  }
}

// ---- gather1 fused: conv1 aggregate + self-loop + bias + ReLU + @W2 -> p2 ----
// 32 lanes per node. NEW: lane j loads ONE distinct csr entry per 32-edge chunk,
// then shfl-broadcasts -> 32x fewer csr VMEM issues; h1 gathers keep 8-deep ILP.
__global__ __launch_bounds__(256) void gather1_kernel(const float* __restrict__ h1,
    const float* __restrict__ dinv, const int* __restrict__ rowptr,
    const int2* __restrict__ csr, const void* __restrict__ b1,
    const void* __restrict__ W2, float* __restrict__ p2,
    const int* __restrict__ flags) {
  __shared__ float w2lds[HID * OUTD];  // [k][m] flat
  __shared__ float b1l[HID];
  __shared__ float tl[8][HID + 1];
  int t = threadIdx.x;
  int isf32 = flags[1];
  w2lds[2 * t]     = ldf(W2, 2 * t, isf32);
  w2lds[2 * t + 1] = ldf(W2, 2 * t + 1, isf32);
  if (t < HID) b1l[t] = ldf(b1, t, isf32);
  __syncthreads();

  int nl = t >> 5;          // node slot 0..7
  int j  = t & 31;          // feature / chunk lane
  int node = blockIdx.x * 8 + nl;
  if (node < NN) {
    int k0 = rowptr[node], k1 = rowptr[node + 1];
    float acc = 0.f;
    for (int base = k0; base < k1; base += 32) {
      int kk = base + j;
      int2 q; q.x = 0; q.y = 0;
      if (kk < k1) q = csr[kk];
      int nloc = min(k1 - base, 32);
      int i = 0;
      for (; i + 8 <= nloc; i += 8) {
        int   s0 = __shfl(q.x, i + 0, 32), s1 = __shfl(q.x, i + 1, 32);
        int   s2 = __shfl(q.x, i + 2, 32), s3 = __shfl(q.x, i + 3, 32);
        int   s4 = __shfl(q.x, i + 4, 32), s5 = __shfl(q.x, i + 5, 32);
        int   s6 = __shfl(q.x, i + 6, 32), s7 = __shfl(q.x, i + 7, 32);
        float w0 = __int_as_float(__shfl(q.y, i + 0, 32));
        float w1 = __int_as_float(__shfl(q.y, i + 1, 32));
        float w2 = __int_as_float(__shfl(q.y, i + 2, 32));
        float w3 = __int_as_float(__shfl(q.y, i + 3, 32));
        float w4 = __int_as_float(__shfl(q.y, i + 4, 32));
        float w5 = __int_as_float(__shfl(q.y, i + 5, 32));
        float w6 = __int_as_float(__shfl(q.y, i + 6, 32));
        float w7 = __int_as_float(__shfl(q.y, i + 7, 32));
        float v0 = h1[s0 * HID + j]; float v1 = h1[s1 * HID + j];
        float v2 = h1[s2 * HID + j]; float v3 = h1[s3 * HID + j];
        float v4 = h1[s4 * HID + j]; float v5 = h1[s5 * HID + j];
        float v6 = h1[s6 * HID + j]; float v7 = h1[s7 * HID + j];
        acc = fmaf(w0, v0, acc); acc = fmaf(w1, v1, acc);
        acc = fmaf(w2, v2, acc); acc = fmaf(w3, v3, acc);
        acc = fmaf(w4, v4, acc); acc = fmaf(w5, v5, acc);
        acc = fmaf(w6, v6, acc); acc = fmaf(w7, v7, acc);
      }
      for (; i < nloc; i++) {
        int   s = __shfl(q.x, i, 32);
        float w = __int_as_float(__shfl(q.y, i, 32));
        acc = fmaf(w, h1[s * HID + j], acc);
      }
    }
    float di = dinv[node];
    acc = fmaf(di * di, h1[node * HID + j], acc);
    acc += b1l[j];
    tl[nl][j] = fmaxf(acc, 0.f);
  }
  __syncthreads();
  int m = t & 31;
  if (node < NN && m < OUTD) {
    float s = 0.f;
    #pragma unroll
    for (int k = 0; k < HID; k++) s = fmaf(tl[nl][k], w2lds[k * OUTD + m], s);
    p2[node * OUTD + m] = s;
  }
}

// ---- gather2: conv2 aggregate + self-loop + bias -> out ----
// 16 lanes per node, shfl-broadcast csr (width 16), 8-deep p2 gather ILP.
__global__ __launch_bounds__(256) void gather2_kernel(const float* __restrict__ p2,
    const float* __restrict__ dinv, const int* __restrict__ rowptr,
    const int2* __restrict__ csr, const void* __restrict__ b2,
    void* __restrict__ out, const int* __restrict__ flags) {
  __shared__ float b2l[OUTD];
  int t = threadIdx.x;
  int isf32 = flags[1];
  if (t < OUTD) b2l[t] = ldf(b2, t, isf32);
  __syncthreads();

  int nl = t >> 4;
  int m  = t & 15;
  int node = blockIdx.x * 16 + nl;
  if (node >= NN) return;
  int k0 = rowptr[node], k1 = rowptr[node + 1];
  float acc = 0.f;
  for (int base = k0; base < k1; base += 16) {
    int kk = base + m;
    int2 q; q.x = 0; q.y = 0;
    if (kk < k1) q = csr[kk];
    int nloc = min(k1 - base, 16);
    int i = 0;
    for (; i + 8 <= nloc; i += 8) {
      int   s0 = __shfl(q.x, i + 0, 16), s1 = __shfl(q.x, i + 1, 16);
      int   s2 = __shfl(q.x, i + 2, 16), s3 = __shfl(q.x, i + 3, 16);
      int   s4 = __shfl(q.x, i + 4, 16), s5 = __shfl(q.x, i + 5, 16);
      int   s6 = __shfl(q.x, i + 6, 16), s7 = __shfl(q.x, i + 7, 16);
      float w0 = __int_as_float(__shfl(q.y, i + 0, 16));
      float w1 = __int_as_float(__shfl(q.y, i + 1, 16));
      float w2 = __int_as_float(__shfl(q.y, i + 2, 16));
      float w3 = __int_as_float(__shfl(q.y, i + 3, 16));
      float w4 = __int_as_float(__shfl(q.y, i + 4, 16));
      float w5 = __int_as_float(__shfl(q.y, i + 5, 16));
      float w6 = __int_as_float(__shfl(q.y, i + 6, 16));
      float w7 = __int_as_float(__shfl(q.y, i + 7, 16));
      float v0 = p2[s0 * OUTD + m]; float v1 = p2[s1 * OUTD + m];
      float v2 = p2[s2 * OUTD + m]; float v3 = p2[s3 * OUTD + m];
      float v4 = p2[s4 * OUTD + m]; float v5 = p2[s5 * OUTD + m];
      float v6 = p2[s6 * OUTD + m]; float v7 = p2[s7 * OUTD + m];
      acc = fmaf(w0, v0, acc); acc = fmaf(w1, v1, acc);
      acc = fmaf(w2, v2, acc); acc = fmaf(w3, v3, acc);
      acc = fmaf(w4, v4, acc); acc = fmaf(w5, v5, acc);
      acc = fmaf(w6, v6, acc); acc = fmaf(w7, v7, acc);
    }
    for (; i < nloc; i++) {
      int   s = __shfl(q.x, i, 16);
      float w = __int_as_float(__shfl(q.y, i, 16));
      acc = fmaf(w, p2[s * OUTD + m], acc);
    }
  }
  float di = dinv[node];
  acc = fmaf(di * di, p2[node * OUTD + m], acc);
  acc += b2l[m];
  int oidx = node * OUTD + m;
  if (isf32) ((float*)out)[oidx] = acc;
  else       ((unsigned short*)out)[oidx] = f2bf(acc);
}

extern "C" void kernel_launch(void* const* d_in, const int* in_sizes, int n_in,
                              void* d_out, int out_size, void* d_ws, size_t ws_size,
                              hipStream_t stream) {
  const void* x  = d_in[0];
  const int* ei  = (const int*)d_in[1];
  const void* ew = d_in[2];
  const void* W1 = d_in[3];
  const void* b1 = d_in[4];
  const void* W2 = d_in[5];
  const void* b2 = d_in[6];
  float* ws = (float*)d_ws;
  int* wsi = (int*)d_ws;
  unsigned long long* degpack = (unsigned long long*)(wsi + OFF_DEGPACK);

  detect_zero_kernel<<<dim3(513), dim3(256), 0, stream>>>(ei, (const unsigned short*)x,
      wsi + OFF_FLAG, ws + OFF_DEGPACK, 2 * NN);
  count_gemm_kernel<<<dim3(FUSE_BLOCKS), dim3(256), 0, stream>>>(ei, ew, degpack,
      wsi + OFF_RANK, x, W1, ws + OFF_H1, wsi + OFF_FLAG);
  dinv_scansum_kernel<<<dim3(2 * NBLK), dim3(256), 0, stream>>>(degpack, ws + OFF_DINV, wsi + OFF_BSUM);
  scan_write_kernel<<<dim3(NBLK), dim3(256), 0, stream>>>(degpack, wsi + OFF_BSUM, wsi + OFF_ROWPTR);
  fill_csr_kernel<<<dim3(FILL_BLOCKS), dim3(256), 0, stream>>>(ei, ew, ws + OFF_DINV,
      wsi + OFF_ROWPTR, wsi + OFF_RANK, (int2*)(wsi + OFF_CSR), wsi + OFF_FLAG);
  gather1_kernel<<<dim3((NN + 7) / 8), dim3(256), 0, stream>>>(ws + OFF_H1, ws + OFF_DINV,
      wsi + OFF_ROWPTR, (const int2*)(wsi + OFF_CSR), b1, W2, ws + OFF_P2, wsi + OFF_FLAG);
  gather2_kernel<<<dim3((NN + 15) / 16), dim3(256), 0, stream>>>(ws + OFF_P2, ws + OFF_DINV,
      wsi + OFF_ROWPTR, (const int2*)(wsi + OFF_CSR), b2, d_out, wsi + OFF_FLAG);
}